// Round 1
// baseline (6159.441 us; speedup 1.0000x reference)
//
#include <hip/hip_runtime.h>

// NeuroVoltron: coupled edge-message + flow + GRU recurrence, T sequential steps.
// Design v1: one block per batch element (64 blocks, 512 threads), full step
// computed in-block with LDS state double-buffering; no inter-block sync needed.

constexpr int R  = 12;
constexpr int L  = 32;
constexpr int M  = 16;
constexpr int HH = 32;
constexpr int HF = 64;
constexpr int E  = 132;   // R*(R-1)
constexpr int G3 = 3 * HH; // 96
constexpr float DT = 0.1f;

__device__ __forceinline__ float sigmoidf(float x) {
    return 1.0f / (1.0f + __expf(-x));
}

// dot of 32 floats (8 x float4), both pointers 16B-aligned
__device__ __forceinline__ float dot32(const float4* __restrict__ w,
                                       const float4* __restrict__ x,
                                       float acc) {
#pragma unroll
    for (int k = 0; k < 8; ++k) {
        float4 a = w[k], b = x[k];
        acc = fmaf(a.x, b.x, acc);
        acc = fmaf(a.y, b.y, acc);
        acc = fmaf(a.z, b.z, acc);
        acc = fmaf(a.w, b.w, acc);
    }
    return acc;
}

__global__ __launch_bounds__(512) void nv_step_kernel(
    const float* __restrict__ z0,      const float* __restrict__ h0,
    const float* __restrict__ mean_w,  const float* __restrict__ mean_b,
    const float* __restrict__ add_w,
    const float* __restrict__ gsw,     const float* __restrict__ gsb,
    const float* __restrict__ gcw,
    const float* __restrict__ lw,      const float* __restrict__ lb,
    const float* __restrict__ ow,      const float* __restrict__ ob,
    const float* __restrict__ wih,     const float* __restrict__ whh,
    const float* __restrict__ bih,     const float* __restrict__ bhh,
    const int* __restrict__ src_idx,   const int* __restrict__ tgt_idx,
    const int* __restrict__ n_steps_p,
    float* __restrict__ out)
{
    const int b   = blockIdx.x;
    const int Bn  = gridDim.x;
    const int tid = threadIdx.x;
    const int T   = n_steps_p[0];

    // output layout: z_traj (B,T,R,L) | h_f (B,R,HH) | msgs (B,T,E,M)
    float* __restrict__ out_z    = out;
    float* __restrict__ out_hf   = out + (size_t)Bn * T * R * L;
    float* __restrict__ out_msgs = out_hf + (size_t)Bn * R * HH;

    __shared__ __align__(16) float zbuf[2][R * L];
    __shared__ __align__(16) float hbuf[2][R * HH];
    __shared__ __align__(16) float incS[R * L];
    __shared__ __align__(16) float meanS[E * M];
    __shared__ __align__(16) float gateS[R * L];
    __shared__ __align__(16) float shS[R * HF];
    __shared__ __align__(16) float giS[R * G3];
    __shared__ __align__(16) float ghS[R * G3];
    __shared__ int srcS[E];
    __shared__ int invS[R * 11];   // edges targeting room r

    // ---- init: state + edge tables ----
    for (int i = tid; i < R * L; i += 512) zbuf[0][i] = z0[(size_t)b * R * L + i];
    for (int i = tid; i < R * HH; i += 512) hbuf[0][i] = h0[(size_t)b * R * HH + i];
    for (int i = tid; i < E; i += 512) srcS[i] = src_idx[i];
    if (tid < R) {
        int cnt = 0;
        for (int e = 0; e < E; ++e)
            if (tgt_idx[e] == tid) invS[tid * 11 + (cnt++)] = e;
    }
    __syncthreads();

    int cur = 0;
    for (int t = 0; t < T; ++t) {
        const float* __restrict__ z = zbuf[cur];
        const float* __restrict__ h = hbuf[cur];
        float* __restrict__ zn = zbuf[cur ^ 1];
        float* __restrict__ hn = hbuf[cur ^ 1];

        // ---- Phase A: mean[e,m] = z[src(e),:] . mean_w[e,m,:] + mean_b ----
        {
            float* __restrict__ msg_out = out_msgs + ((size_t)b * T + t) * (E * M);
            for (int idx = tid; idx < E * M; idx += 512) {
                const int e = idx >> 4;       // /M
                const int s = srcS[e];
                float acc = mean_b[idx];
                acc = dot32(reinterpret_cast<const float4*>(mean_w + (size_t)idx * L),
                            reinterpret_cast<const float4*>(z + s * L), acc);
                meanS[idx] = acc;
                msg_out[idx] = acc;
            }
        }
        __syncthreads();

        // ---- Phase B: inc[r,l] = sum_{e:tgt=r} mean[e,:] . add_w[e,l,:] ----
        if (tid < R * L) {
            const int r = tid >> 5;
            const int l = tid & 31;
            float acc = 0.0f;
#pragma unroll
            for (int k = 0; k < 11; ++k) {
                const int e = invS[r * 11 + k];
                const float4* wp = reinterpret_cast<const float4*>(add_w + ((size_t)e * L + l) * M);
                const float4* mp = reinterpret_cast<const float4*>(meanS + e * M);
#pragma unroll
                for (int q = 0; q < 4; ++q) {
                    float4 a = wp[q], c = mp[q];
                    acc = fmaf(a.x, c.x, acc);
                    acc = fmaf(a.y, c.y, acc);
                    acc = fmaf(a.z, c.z, acc);
                    acc = fmaf(a.w, c.w, acc);
                }
            }
            incS[tid] = acc;
        }
        __syncthreads();

        // ---- Phase C: gate (384) | silu layer (768) | GRU gi/gh (1152) ----
        for (int idx = tid; idx < 384 + 768 + 1152; idx += 512) {
            if (idx < 384) {
                const int r = idx >> 5;
                float acc = gsb[idx];
                acc = dot32(reinterpret_cast<const float4*>(gsw + (size_t)idx * L),
                            reinterpret_cast<const float4*>(z + r * L), acc);
                acc = dot32(reinterpret_cast<const float4*>(gcw + (size_t)idx * L),
                            reinterpret_cast<const float4*>(incS + r * L), acc);
                gateS[idx] = sigmoidf(acc);
            } else if (idx < 384 + 768) {
                const int j = idx - 384;      // r*HF + f
                const int r = j >> 6;
                float pre = lb[j];
                const float* wrow = lw + (size_t)j * (2 * L);
                pre = dot32(reinterpret_cast<const float4*>(wrow),
                            reinterpret_cast<const float4*>(z + r * L), pre);
                pre = dot32(reinterpret_cast<const float4*>(wrow + L),
                            reinterpret_cast<const float4*>(incS + r * L), pre);
                shS[j] = pre * sigmoidf(pre);   // silu
            } else {
                const int j = idx - 1152;     // r*96 + jj
                const int r = j / G3;
                float gi = bih[j];
                gi = dot32(reinterpret_cast<const float4*>(wih + (size_t)j * L),
                           reinterpret_cast<const float4*>(incS + r * L), gi);
                float gh = bhh[j];
                gh = dot32(reinterpret_cast<const float4*>(whh + (size_t)j * HH),
                           reinterpret_cast<const float4*>(h + r * HH), gh);
                giS[j] = gi;
                ghS[j] = gh;
            }
        }
        __syncthreads();

        // ---- Phase D: target/tanh + z update (384) | GRU combine (384) ----
        for (int idx = tid; idx < 768; idx += 512) {
            if (idx < 384) {
                const int r = idx >> 5;
                float acc = ob[idx];
                const float4* wp = reinterpret_cast<const float4*>(ow + (size_t)idx * HF);
                const float4* hp = reinterpret_cast<const float4*>(shS + r * HF);
#pragma unroll
                for (int k = 0; k < 16; ++k) {
                    float4 a = wp[k], c = hp[k];
                    acc = fmaf(a.x, c.x, acc);
                    acc = fmaf(a.y, c.y, acc);
                    acc = fmaf(a.z, c.z, acc);
                    acc = fmaf(a.w, c.w, acc);
                }
                const float target = tanhf(acc);
                const float zv = z[idx];
                const float znew = zv + DT * gateS[idx] * (target - zv);
                zn[idx] = znew;
                out_z[((size_t)b * T + t) * (R * L) + idx] = znew;
            } else {
                const int j  = idx - 384;     // r*HH + hh
                const int r  = j >> 5;
                const int hh = j & 31;
                const float ir = giS[r * G3 + hh];
                const float iz = giS[r * G3 + HH + hh];
                const float in_ = giS[r * G3 + 2 * HH + hh];
                const float hr = ghS[r * G3 + hh];
                const float hz = ghS[r * G3 + HH + hh];
                const float hnv = ghS[r * G3 + 2 * HH + hh];
                const float reset = sigmoidf(ir + hr);
                const float upd   = sigmoidf(iz + hz);
                const float nw    = tanhf(in_ + reset * hnv);
                hn[j] = (1.0f - upd) * nw + upd * h[j];
            }
        }
        __syncthreads();
        cur ^= 1;
    }

    // ---- final h ----
    for (int i = tid; i < R * HH; i += 512)
        out_hf[(size_t)b * R * HH + i] = hbuf[cur][i];
}

extern "C" void kernel_launch(void* const* d_in, const int* in_sizes, int n_in,
                              void* d_out, int out_size, void* d_ws, size_t ws_size,
                              hipStream_t stream) {
    const float* z0     = (const float*)d_in[0];
    const float* h0     = (const float*)d_in[1];
    const float* mean_w = (const float*)d_in[2];
    const float* mean_b = (const float*)d_in[3];
    const float* add_w  = (const float*)d_in[4];
    const float* gsw    = (const float*)d_in[5];
    const float* gsb    = (const float*)d_in[6];
    const float* gcw    = (const float*)d_in[7];
    const float* lw     = (const float*)d_in[8];
    const float* lb     = (const float*)d_in[9];
    const float* ow     = (const float*)d_in[10];
    const float* ob     = (const float*)d_in[11];
    const float* wih    = (const float*)d_in[12];
    const float* whh    = (const float*)d_in[13];
    const float* bih    = (const float*)d_in[14];
    const float* bhh    = (const float*)d_in[15];
    const int* src_idx  = (const int*)d_in[16];
    const int* tgt_idx  = (const int*)d_in[17];
    const int* n_steps  = (const int*)d_in[18];

    const int B = in_sizes[0] / (R * L);

    nv_step_kernel<<<dim3(B), dim3(512), 0, stream>>>(
        z0, h0, mean_w, mean_b, add_w, gsw, gsb, gcw, lw, lb, ow, ob,
        wih, whh, bih, bhh, src_idx, tgt_idx, n_steps, (float*)d_out);
}

// Round 2
// 4863.705 us; speedup vs baseline: 1.2664x; 1.2664x over previous
//
#include <hip/hip_runtime.h>

// NeuroVoltron v2: 4 shard-blocks per batch element (grid = 4 x 64 = 256 blocks),
// pre-transposed (coalesced) weights in d_ws, per-batch 4-block atomic barrier
// for z exchange each step. h/gates/GRU are room-local to a shard.

constexpr int R  = 12;
constexpr int L  = 32;
constexpr int M  = 16;
constexpr int HH = 32;
constexpr int HF = 64;
constexpr int E  = 132;
constexpr int G3 = 96;     // 3*HH
constexpr float DT = 0.1f;

constexpr int NSHARD = 4;  // blocks per batch element
constexpr int RPS    = 3;  // rooms per shard
constexpr int EPS    = 33; // edges per shard (11 per target room)
constexpr int BS     = 512;

// transposed-weight sizes (floats)
constexpr int SZ_MEAN = E * M * L;      // 67584
constexpr int SZ_ADD  = E * L * M;      // 67584
constexpr int SZ_GS   = R * L * L;      // 12288
constexpr int SZ_LW   = R * HF * 2 * L; // 49152
constexpr int SZ_OW   = R * L * HF;     // 24576
constexpr int SZ_WIH  = R * G3 * L;     // 36864
constexpr int SZ_XW   = SZ_MEAN + SZ_ADD + 2 * SZ_GS + SZ_LW + SZ_OW + 2 * SZ_WIH; // 307200

__device__ __forceinline__ float sigmoidf(float x) {
    return 1.0f / (1.0f + __expf(-x));
}
__device__ __forceinline__ float fma4(float4 a, float4 x, float acc) {
    acc = fmaf(a.x, x.x, acc);
    acc = fmaf(a.y, x.y, acc);
    acc = fmaf(a.z, x.z, acc);
    return fmaf(a.w, x.w, acc);
}

// ---- prep: transpose weights into [k/4][j][4] packed layout; zero barriers ----
__global__ void nv_prep(const float* __restrict__ mean_w, const float* __restrict__ add_w,
                        const float* __restrict__ gsw,    const float* __restrict__ gcw,
                        const float* __restrict__ lw,     const float* __restrict__ ow,
                        const float* __restrict__ wih,    const float* __restrict__ whh,
                        float* __restrict__ xw, unsigned int* __restrict__ bar, int nbar) {
    int i = blockIdx.x * blockDim.x + threadIdx.x;
    int base = 0;
    // mean: J=2112, K=32
    if (i < SZ_MEAN) {
        int j = i >> 5, k = i & 31;
        xw[(((k >> 2) * 2112 + j) << 2) + (k & 3)] = mean_w[i];
        return;
    }
    i -= SZ_MEAN; base += SZ_MEAN;
    // add: per-edge J=32(l), K=16(m)
    if (i < SZ_ADD) {
        int e = i >> 9, rem = i & 511, l = rem >> 4, m = rem & 15;
        xw[base + ((((e * 4 + (m >> 2)) * 32 + l) << 2) + (m & 3))] = add_w[i];
        return;
    }
    i -= SZ_ADD; base += SZ_ADD;
    // gs: J=384, K=32
    if (i < SZ_GS) {
        int j = i >> 5, k = i & 31;
        xw[base + (((k >> 2) * 384 + j) << 2) + (k & 3)] = gsw[i];
        return;
    }
    i -= SZ_GS; base += SZ_GS;
    if (i < SZ_GS) {
        int j = i >> 5, k = i & 31;
        xw[base + (((k >> 2) * 384 + j) << 2) + (k & 3)] = gcw[i];
        return;
    }
    i -= SZ_GS; base += SZ_GS;
    // lw: J=768, K=64
    if (i < SZ_LW) {
        int j = i >> 6, k = i & 63;
        xw[base + (((k >> 2) * 768 + j) << 2) + (k & 3)] = lw[i];
        return;
    }
    i -= SZ_LW; base += SZ_LW;
    // ow: J=384, K=64
    if (i < SZ_OW) {
        int j = i >> 6, k = i & 63;
        xw[base + (((k >> 2) * 384 + j) << 2) + (k & 3)] = ow[i];
        return;
    }
    i -= SZ_OW; base += SZ_OW;
    // wih: J=1152, K=32
    if (i < SZ_WIH) {
        int j = i >> 5, k = i & 31;
        xw[base + (((k >> 2) * 1152 + j) << 2) + (k & 3)] = wih[i];
        return;
    }
    i -= SZ_WIH; base += SZ_WIH;
    if (i < SZ_WIH) {
        int j = i >> 5, k = i & 31;
        xw[base + (((k >> 2) * 1152 + j) << 2) + (k & 3)] = whh[i];
        return;
    }
    i -= SZ_WIH;
    if (i < nbar) bar[i] = 0u;
}

__global__ __launch_bounds__(BS) void nv_main(
    const float* __restrict__ z0,  const float* __restrict__ h0,
    const float* __restrict__ mean_b, const float* __restrict__ gsb,
    const float* __restrict__ lb,  const float* __restrict__ ob,
    const float* __restrict__ bih, const float* __restrict__ bhh,
    const int* __restrict__ src_idx, const int* __restrict__ tgt_idx,
    const int* __restrict__ n_steps_p,
    const float* __restrict__ xw,
    float* __restrict__ zx, unsigned int* __restrict__ bar,
    float* __restrict__ out, int B)
{
    const int s = blockIdx.x;   // shard
    const int b = blockIdx.y;   // batch
    const int tid = threadIdx.x;
    const int T = n_steps_p[0];

    const float4* xmean = (const float4*)(xw);
    const float4* xadd  = (const float4*)(xw + SZ_MEAN);
    const float4* xgs   = (const float4*)(xw + SZ_MEAN + SZ_ADD);
    const float4* xgc   = (const float4*)(xw + SZ_MEAN + SZ_ADD + SZ_GS);
    const float4* xlw   = (const float4*)(xw + SZ_MEAN + SZ_ADD + 2 * SZ_GS);
    const float4* xow   = (const float4*)(xw + SZ_MEAN + SZ_ADD + 2 * SZ_GS + SZ_LW);
    const float4* xwih  = (const float4*)(xw + SZ_MEAN + SZ_ADD + 2 * SZ_GS + SZ_LW + SZ_OW);
    const float4* xwhh  = (const float4*)(xw + SZ_MEAN + SZ_ADD + 2 * SZ_GS + SZ_LW + SZ_OW + SZ_WIH);

    float* __restrict__ out_z    = out;
    float* __restrict__ out_hf   = out + (size_t)B * T * R * L;
    float* __restrict__ out_msgs = out_hf + (size_t)B * R * HH;

    __shared__ __align__(16) float z_all[R * L];
    __shared__ __align__(16) float h_own[RPS * HH];
    __shared__ __align__(16) float meanS[EPS * M];
    __shared__ __align__(16) float incS[RPS * L];
    __shared__ __align__(16) float gateS[RPS * L];
    __shared__ __align__(16) float shS[RPS * HF];
    __shared__ __align__(16) float giS[RPS * G3];
    __shared__ __align__(16) float ghS[RPS * G3];
    __shared__ int edgeE[EPS], edgeSrc[EPS];

    for (int i = tid; i < R * L; i += BS) z_all[i] = z0[(size_t)b * R * L + i];
    for (int i = tid; i < RPS * HH; i += BS) h_own[i] = h0[(size_t)b * R * HH + s * RPS * HH + i];
    if (tid < RPS) {
        const int r = s * RPS + tid;
        int cnt = 0;
        for (int e = 0; e < E; ++e)
            if (tgt_idx[e] == r) { edgeE[tid * 11 + cnt] = e; edgeSrc[tid * 11 + cnt] = src_idx[e]; ++cnt; }
    }
    __syncthreads();

    const float4* z4   = (const float4*)z_all;
    const float4* h4   = (const float4*)h_own;
    const float4* inc4 = (const float4*)incS;
    const float4* m4   = (const float4*)meanS;
    const float4* sh4  = (const float4*)shS;

    for (int t = 0; t < T; ++t) {
        // ---- Phase A: mean for owned (target-sharded) edges ----
        {
            float* __restrict__ msg_out = out_msgs + ((size_t)b * T + t) * (E * M);
            for (int idx = tid; idx < EPS * M; idx += BS) {
                const int le = idx >> 4, m = idx & 15;
                const int eg = edgeE[le];
                const int jg = eg * 16 + m;
                const int sr = edgeSrc[le];
                float acc = mean_b[jg];
#pragma unroll
                for (int c = 0; c < 8; ++c)
                    acc = fma4(xmean[c * 2112 + jg], z4[sr * 8 + c], acc);
                meanS[idx] = acc;
                msg_out[(size_t)eg * 16 + m] = acc;
            }
        }
        __syncthreads();

        // ---- Phase B: inc[rr,l] over 11 incoming edges ----
        if (tid < RPS * L) {
            const int rr = tid >> 5, l = tid & 31;
            float acc = 0.0f;
#pragma unroll
            for (int i = 0; i < 11; ++i) {
                const int eg = edgeE[rr * 11 + i];
#pragma unroll
                for (int c = 0; c < 4; ++c)
                    acc = fma4(xadd[(eg * 4 + c) * 32 + l], m4[(rr * 11 + i) * 4 + c], acc);
            }
            incS[tid] = acc;
        }
        __syncthreads();

        // ---- Phase C: gate(96) | silu(192) | gi(288) | gh(288) ----
        for (int idx = tid; idx < 864; idx += BS) {
            if (idx < 96) {
                const int rr = idx >> 5;
                const int jg = s * 96 + idx;
                float acc = gsb[jg];
#pragma unroll
                for (int c = 0; c < 8; ++c) {
                    acc = fma4(xgs[c * 384 + jg], z4[(s * RPS + rr) * 8 + c], acc);
                    acc = fma4(xgc[c * 384 + jg], inc4[rr * 8 + c], acc);
                }
                gateS[idx] = sigmoidf(acc);
            } else if (idx < 288) {
                const int jl = idx - 96;
                const int rr = jl >> 6;
                const int jg = s * 192 + jl;
                float acc = lb[jg];
#pragma unroll
                for (int c = 0; c < 8; ++c) {
                    acc = fma4(xlw[c * 768 + jg], z4[(s * RPS + rr) * 8 + c], acc);
                    acc = fma4(xlw[(8 + c) * 768 + jg], inc4[rr * 8 + c], acc);
                }
                shS[jl] = acc * sigmoidf(acc);
            } else if (idx < 576) {
                const int jl = idx - 288;
                const int rr = jl / 96;
                const int jg = s * 288 + jl;
                float acc = bih[jg];
#pragma unroll
                for (int c = 0; c < 8; ++c)
                    acc = fma4(xwih[c * 1152 + jg], inc4[rr * 8 + c], acc);
                giS[jl] = acc;
            } else {
                const int jl = idx - 576;
                const int rr = jl / 96;
                const int jg = s * 288 + jl;
                float acc = bhh[jg];
#pragma unroll
                for (int c = 0; c < 8; ++c)
                    acc = fma4(xwhh[c * 1152 + jg], h4[rr * 8 + c], acc);
                ghS[jl] = acc;
            }
        }
        __syncthreads();

        // ---- Phase D: z update (96) | GRU combine (96) ----
        const int p = t & 1;
        float* __restrict__ zxp = zx + ((size_t)p * B + b) * (R * L);
        if (tid < 192) {
            if (tid < 96) {
                const int rr = tid >> 5;
                const int jg = s * 96 + tid;
                float acc = ob[jg];
#pragma unroll
                for (int c = 0; c < 16; ++c)
                    acc = fma4(xow[c * 384 + jg], sh4[rr * 16 + c], acc);
                const float target = tanhf(acc);
                const float zold = z_all[s * 96 + tid];
                const float znew = zold + DT * gateS[tid] * (target - zold);
                __hip_atomic_store(&zxp[s * 96 + tid], znew, __ATOMIC_RELAXED, __HIP_MEMORY_SCOPE_AGENT);
                out_z[((size_t)b * T + t) * (R * L) + s * 96 + tid] = znew;
            } else {
                const int jl = tid - 96;
                const int rr = jl >> 5, hh = jl & 31;
                const float ir  = giS[rr * G3 + hh];
                const float iz  = giS[rr * G3 + HH + hh];
                const float inn = giS[rr * G3 + 2 * HH + hh];
                const float hr  = ghS[rr * G3 + hh];
                const float hz  = ghS[rr * G3 + HH + hh];
                const float hnv = ghS[rr * G3 + 2 * HH + hh];
                const float reset = sigmoidf(ir + hr);
                const float upd   = sigmoidf(iz + hz);
                const float nw    = tanhf(inn + reset * hnv);
                h_own[jl] = (1.0f - upd) * nw + upd * h_own[jl];
            }
        }
        __syncthreads();

        // ---- 4-block barrier for this batch element (monotonic counter) ----
        if (tid == 0) {
            __hip_atomic_fetch_add(&bar[b], 1u, __ATOMIC_RELEASE, __HIP_MEMORY_SCOPE_AGENT);
            const unsigned int target = (unsigned int)NSHARD * (unsigned int)(t + 1);
            while (__hip_atomic_load(&bar[b], __ATOMIC_ACQUIRE, __HIP_MEMORY_SCOPE_AGENT) < target)
                __builtin_amdgcn_s_sleep(1);
        }
        __syncthreads();

        // ---- refresh full z from exchange buffer ----
        for (int i = tid; i < R * L; i += BS)
            z_all[i] = __hip_atomic_load(&zxp[i], __ATOMIC_RELAXED, __HIP_MEMORY_SCOPE_AGENT);
        __syncthreads();
    }

    for (int i = tid; i < RPS * HH; i += BS)
        out_hf[(size_t)b * R * HH + s * RPS * HH + i] = h_own[i];
}

extern "C" void kernel_launch(void* const* d_in, const int* in_sizes, int n_in,
                              void* d_out, int out_size, void* d_ws, size_t ws_size,
                              hipStream_t stream) {
    const float* z0     = (const float*)d_in[0];
    const float* h0     = (const float*)d_in[1];
    const float* mean_w = (const float*)d_in[2];
    const float* mean_b = (const float*)d_in[3];
    const float* add_w  = (const float*)d_in[4];
    const float* gsw    = (const float*)d_in[5];
    const float* gsb    = (const float*)d_in[6];
    const float* gcw    = (const float*)d_in[7];
    const float* lw     = (const float*)d_in[8];
    const float* lb     = (const float*)d_in[9];
    const float* ow     = (const float*)d_in[10];
    const float* ob     = (const float*)d_in[11];
    const float* wih    = (const float*)d_in[12];
    const float* whh    = (const float*)d_in[13];
    const float* bih    = (const float*)d_in[14];
    const float* bhh    = (const float*)d_in[15];
    const int* src_idx  = (const int*)d_in[16];
    const int* tgt_idx  = (const int*)d_in[17];
    const int* n_steps  = (const int*)d_in[18];

    const int B = in_sizes[0] / (R * L);

    float* wsf = (float*)d_ws;
    float* xw  = wsf;                              // SZ_XW floats
    float* zx  = wsf + SZ_XW;                      // 2*B*R*L floats
    unsigned int* bar = (unsigned int*)(wsf + SZ_XW + 2 * (size_t)B * R * L); // B uints

    const int prep_items = SZ_XW + B;              // transposes + barrier zeroing
    nv_prep<<<dim3((prep_items + 255) / 256), dim3(256), 0, stream>>>(
        mean_w, add_w, gsw, gcw, lw, ow, wih, whh, xw, bar, B);

    nv_main<<<dim3(NSHARD, B), dim3(BS), 0, stream>>>(
        z0, h0, mean_b, gsb, lb, ob, bih, bhh, src_idx, tgt_idx, n_steps,
        xw, zx, bar, (float*)d_out, B);
}

// Round 4
// 3301.873 us; speedup vs baseline: 1.8654x; 1.4730x over previous
//
#include <hip/hip_runtime.h>

// NeuroVoltron v3b: v2 structure (4 shard-blocks per batch, transposed weights)
// + padded per-batch barrier lines (256B each), relaxed polling + single acquire
// fence (__builtin_amdgcn_fence), 4-way K-split Phase B, gh merged into Phase A,
// nontemporal output stores.

constexpr int R  = 12;
constexpr int L  = 32;
constexpr int M  = 16;
constexpr int HH = 32;
constexpr int HF = 64;
constexpr int E  = 132;
constexpr int G3 = 96;     // 3*HH
constexpr float DT = 0.1f;

constexpr int NSHARD = 4;  // blocks per batch element
constexpr int RPS    = 3;  // rooms per shard
constexpr int EPS    = 33; // edges per shard (11 per target room)
constexpr int BS     = 512;
constexpr int BARSTRIDE = 64; // uints per barrier counter (256 B line)

// transposed-weight sizes (floats)
constexpr int SZ_MEAN = E * M * L;      // 67584
constexpr int SZ_ADD  = E * L * M;      // 67584
constexpr int SZ_GS   = R * L * L;      // 12288
constexpr int SZ_LW   = R * HF * 2 * L; // 49152
constexpr int SZ_OW   = R * L * HF;     // 24576
constexpr int SZ_WIH  = R * G3 * L;     // 36864
constexpr int SZ_XW   = SZ_MEAN + SZ_ADD + 2 * SZ_GS + SZ_LW + SZ_OW + 2 * SZ_WIH; // 307200

__device__ __forceinline__ float sigmoidf(float x) {
    return 1.0f / (1.0f + __expf(-x));
}
__device__ __forceinline__ float fma4(float4 a, float4 x, float acc) {
    acc = fmaf(a.x, x.x, acc);
    acc = fmaf(a.y, x.y, acc);
    acc = fmaf(a.z, x.z, acc);
    return fmaf(a.w, x.w, acc);
}

// ---- prep: transpose weights into [k/4][j][4] packed layout; zero barriers ----
__global__ void nv_prep(const float* __restrict__ mean_w, const float* __restrict__ add_w,
                        const float* __restrict__ gsw,    const float* __restrict__ gcw,
                        const float* __restrict__ lw,     const float* __restrict__ ow,
                        const float* __restrict__ wih,    const float* __restrict__ whh,
                        float* __restrict__ xw, unsigned int* __restrict__ bar, int nbar) {
    int i = blockIdx.x * blockDim.x + threadIdx.x;
    int base = 0;
    if (i < SZ_MEAN) {
        int j = i >> 5, k = i & 31;
        xw[(((k >> 2) * 2112 + j) << 2) + (k & 3)] = mean_w[i];
        return;
    }
    i -= SZ_MEAN; base += SZ_MEAN;
    if (i < SZ_ADD) {
        int e = i >> 9, rem = i & 511, l = rem >> 4, m = rem & 15;
        xw[base + ((((e * 4 + (m >> 2)) * 32 + l) << 2) + (m & 3))] = add_w[i];
        return;
    }
    i -= SZ_ADD; base += SZ_ADD;
    if (i < SZ_GS) {
        int j = i >> 5, k = i & 31;
        xw[base + (((k >> 2) * 384 + j) << 2) + (k & 3)] = gsw[i];
        return;
    }
    i -= SZ_GS; base += SZ_GS;
    if (i < SZ_GS) {
        int j = i >> 5, k = i & 31;
        xw[base + (((k >> 2) * 384 + j) << 2) + (k & 3)] = gcw[i];
        return;
    }
    i -= SZ_GS; base += SZ_GS;
    if (i < SZ_LW) {
        int j = i >> 6, k = i & 63;
        xw[base + (((k >> 2) * 768 + j) << 2) + (k & 3)] = lw[i];
        return;
    }
    i -= SZ_LW; base += SZ_LW;
    if (i < SZ_OW) {
        int j = i >> 6, k = i & 63;
        xw[base + (((k >> 2) * 384 + j) << 2) + (k & 3)] = ow[i];
        return;
    }
    i -= SZ_OW; base += SZ_OW;
    if (i < SZ_WIH) {
        int j = i >> 5, k = i & 31;
        xw[base + (((k >> 2) * 1152 + j) << 2) + (k & 3)] = wih[i];
        return;
    }
    i -= SZ_WIH; base += SZ_WIH;
    if (i < SZ_WIH) {
        int j = i >> 5, k = i & 31;
        xw[base + (((k >> 2) * 1152 + j) << 2) + (k & 3)] = whh[i];
        return;
    }
    i -= SZ_WIH;
    if (i < nbar) bar[i] = 0u;
}

__global__ __launch_bounds__(BS) void nv_main(
    const float* __restrict__ z0,  const float* __restrict__ h0,
    const float* __restrict__ mean_b, const float* __restrict__ gsb,
    const float* __restrict__ lb,  const float* __restrict__ ob,
    const float* __restrict__ bih, const float* __restrict__ bhh,
    const int* __restrict__ src_idx, const int* __restrict__ tgt_idx,
    const int* __restrict__ n_steps_p,
    const float* __restrict__ xw,
    float* __restrict__ zx, unsigned int* __restrict__ bar,
    float* __restrict__ out, int B)
{
    const int s = blockIdx.x;   // shard
    const int b = blockIdx.y;   // batch
    const int tid = threadIdx.x;
    const int T = n_steps_p[0];

    const float4* xmean = (const float4*)(xw);
    const float4* xadd  = (const float4*)(xw + SZ_MEAN);
    const float4* xgs   = (const float4*)(xw + SZ_MEAN + SZ_ADD);
    const float4* xgc   = (const float4*)(xw + SZ_MEAN + SZ_ADD + SZ_GS);
    const float4* xlw   = (const float4*)(xw + SZ_MEAN + SZ_ADD + 2 * SZ_GS);
    const float4* xow   = (const float4*)(xw + SZ_MEAN + SZ_ADD + 2 * SZ_GS + SZ_LW);
    const float4* xwih  = (const float4*)(xw + SZ_MEAN + SZ_ADD + 2 * SZ_GS + SZ_LW + SZ_OW);
    const float4* xwhh  = (const float4*)(xw + SZ_MEAN + SZ_ADD + 2 * SZ_GS + SZ_LW + SZ_OW + SZ_WIH);

    float* __restrict__ out_z    = out;
    float* __restrict__ out_hf   = out + (size_t)B * T * R * L;
    float* __restrict__ out_msgs = out_hf + (size_t)B * R * HH;

    __shared__ __align__(16) float z_all[R * L];
    __shared__ __align__(16) float h_own[RPS * HH];
    __shared__ __align__(16) float meanS[EPS * M];
    __shared__ __align__(16) float incP[4][RPS * L];
    __shared__ __align__(16) float incS[RPS * L];
    __shared__ __align__(16) float gateS[RPS * L];
    __shared__ __align__(16) float shS[RPS * HF];
    __shared__ __align__(16) float giS[RPS * G3];
    __shared__ __align__(16) float ghS[RPS * G3];
    __shared__ int edgeE[EPS], edgeSrc[EPS];

    for (int i = tid; i < R * L; i += BS) z_all[i] = z0[(size_t)b * R * L + i];
    for (int i = tid; i < RPS * HH; i += BS) h_own[i] = h0[(size_t)b * R * HH + s * RPS * HH + i];
    if (tid < RPS) {
        const int r = s * RPS + tid;
        int cnt = 0;
        for (int e = 0; e < E; ++e)
            if (tgt_idx[e] == r) { edgeE[tid * 11 + cnt] = e; edgeSrc[tid * 11 + cnt] = src_idx[e]; ++cnt; }
    }
    __syncthreads();

    const float4* z4   = (const float4*)z_all;
    const float4* h4   = (const float4*)h_own;
    const float4* inc4 = (const float4*)incS;
    const float4* m4   = (const float4*)meanS;
    const float4* sh4  = (const float4*)shS;

    unsigned int* __restrict__ mybar = &bar[(size_t)b * BARSTRIDE];

    for (int t = 0; t < T; ++t) {
        // ---- Phase A: mean (528) | gh (288, depends only on h) ----
        {
            float* __restrict__ msg_out = out_msgs + ((size_t)b * T + t) * (E * M);
            for (int idx = tid; idx < 528 + 288; idx += BS) {
                if (idx < 528) {
                    const int le = idx >> 4, m = idx & 15;
                    const int eg = edgeE[le];
                    const int jg = eg * 16 + m;
                    const int sr = edgeSrc[le];
                    float acc = mean_b[jg];
#pragma unroll
                    for (int c = 0; c < 8; ++c)
                        acc = fma4(xmean[c * 2112 + jg], z4[sr * 8 + c], acc);
                    meanS[idx] = acc;
                    __builtin_nontemporal_store(acc, &msg_out[(size_t)eg * 16 + m]);
                } else {
                    const int jl = idx - 528;     // rr*96 + jj
                    const int rr = jl / 96;
                    const int jg = s * 288 + jl;
                    float acc = bhh[jg];
#pragma unroll
                    for (int c = 0; c < 8; ++c)
                        acc = fma4(xwhh[c * 1152 + jg], h4[rr * 8 + c], acc);
                    ghS[jl] = acc;
                }
            }
        }
        __syncthreads();

        // ---- Phase B: 4-way K-split partial inc ----
        if (tid < 384) {
            const int q  = tid / 96;          // edge-chunk
            const int j  = tid - q * 96;      // rr*32 + l
            const int rr = j >> 5, l = j & 31;
            const int e0 = q * 3;
            const int e1 = (q == 3) ? 11 : e0 + 3;
            float acc = 0.0f;
            for (int i = e0; i < e1; ++i) {
                const int eg = edgeE[rr * 11 + i];
#pragma unroll
                for (int c = 0; c < 4; ++c)
                    acc = fma4(xadd[(eg * 4 + c) * 32 + l], m4[(rr * 11 + i) * 4 + c], acc);
            }
            incP[q][j] = acc;
        }
        __syncthreads();
        if (tid < RPS * L)
            incS[tid] = incP[0][tid] + incP[1][tid] + incP[2][tid] + incP[3][tid];
        __syncthreads();

        // ---- Phase C: gate(96) | silu(192) | gi(288) ----
        for (int idx = tid; idx < 576; idx += BS) {
            if (idx < 96) {
                const int rr = idx >> 5;
                const int jg = s * 96 + idx;
                float acc = gsb[jg];
#pragma unroll
                for (int c = 0; c < 8; ++c) {
                    acc = fma4(xgs[c * 384 + jg], z4[(s * RPS + rr) * 8 + c], acc);
                    acc = fma4(xgc[c * 384 + jg], inc4[rr * 8 + c], acc);
                }
                gateS[idx] = sigmoidf(acc);
            } else if (idx < 288) {
                const int jl = idx - 96;
                const int rr = jl >> 6;
                const int jg = s * 192 + jl;
                float acc = lb[jg];
#pragma unroll
                for (int c = 0; c < 8; ++c) {
                    acc = fma4(xlw[c * 768 + jg], z4[(s * RPS + rr) * 8 + c], acc);
                    acc = fma4(xlw[(8 + c) * 768 + jg], inc4[rr * 8 + c], acc);
                }
                shS[jl] = acc * sigmoidf(acc);
            } else {
                const int jl = idx - 288;
                const int rr = jl / 96;
                const int jg = s * 288 + jl;
                float acc = bih[jg];
#pragma unroll
                for (int c = 0; c < 8; ++c)
                    acc = fma4(xwih[c * 1152 + jg], inc4[rr * 8 + c], acc);
                giS[jl] = acc;
            }
        }
        __syncthreads();

        // ---- Phase D: z update (96) | GRU combine (96) ----
        const int p = t & 1;
        float* __restrict__ zxp = zx + ((size_t)p * B + b) * (R * L);
        if (tid < 192) {
            if (tid < 96) {
                const int rr = tid >> 5;
                const int jg = s * 96 + tid;
                float acc = ob[jg];
#pragma unroll
                for (int c = 0; c < 16; ++c)
                    acc = fma4(xow[c * 384 + jg], sh4[rr * 16 + c], acc);
                const float target = tanhf(acc);
                const float zold = z_all[s * 96 + tid];
                const float znew = zold + DT * gateS[tid] * (target - zold);
                __hip_atomic_store(&zxp[s * 96 + tid], znew, __ATOMIC_RELAXED, __HIP_MEMORY_SCOPE_AGENT);
                __builtin_nontemporal_store(znew, &out_z[((size_t)b * T + t) * (R * L) + s * 96 + tid]);
            } else {
                const int jl = tid - 96;
                const int rr = jl >> 5, hh = jl & 31;
                const float ir  = giS[rr * G3 + hh];
                const float iz  = giS[rr * G3 + HH + hh];
                const float inn = giS[rr * G3 + 2 * HH + hh];
                const float hr  = ghS[rr * G3 + hh];
                const float hz  = ghS[rr * G3 + HH + hh];
                const float hnv = ghS[rr * G3 + 2 * HH + hh];
                const float reset = sigmoidf(ir + hr);
                const float upd   = sigmoidf(iz + hz);
                const float nw    = tanhf(inn + reset * hnv);
                h_own[jl] = (1.0f - upd) * nw + upd * h_own[jl];
            }
        }
        __syncthreads();

        // ---- 4-block barrier: padded counter line, relaxed poll + 1 acquire ----
        if (tid == 0) {
            __hip_atomic_fetch_add(mybar, 1u, __ATOMIC_RELEASE, __HIP_MEMORY_SCOPE_AGENT);
            const unsigned int target = (unsigned int)NSHARD * (unsigned int)(t + 1);
            while (__hip_atomic_load(mybar, __ATOMIC_RELAXED, __HIP_MEMORY_SCOPE_AGENT) < target)
                __builtin_amdgcn_s_sleep(1);
            __builtin_amdgcn_fence(__ATOMIC_ACQUIRE, "agent");
        }
        __syncthreads();

        // ---- refresh full z from exchange buffer ----
        for (int i = tid; i < R * L; i += BS)
            z_all[i] = __hip_atomic_load(&zxp[i], __ATOMIC_RELAXED, __HIP_MEMORY_SCOPE_AGENT);
        __syncthreads();
    }

    for (int i = tid; i < RPS * HH; i += BS)
        __builtin_nontemporal_store(h_own[i], &out_hf[(size_t)b * R * HH + s * RPS * HH + i]);
}

extern "C" void kernel_launch(void* const* d_in, const int* in_sizes, int n_in,
                              void* d_out, int out_size, void* d_ws, size_t ws_size,
                              hipStream_t stream) {
    const float* z0     = (const float*)d_in[0];
    const float* h0     = (const float*)d_in[1];
    const float* mean_w = (const float*)d_in[2];
    const float* mean_b = (const float*)d_in[3];
    const float* add_w  = (const float*)d_in[4];
    const float* gsw    = (const float*)d_in[5];
    const float* gsb    = (const float*)d_in[6];
    const float* gcw    = (const float*)d_in[7];
    const float* lw     = (const float*)d_in[8];
    const float* lb     = (const float*)d_in[9];
    const float* ow     = (const float*)d_in[10];
    const float* ob     = (const float*)d_in[11];
    const float* wih    = (const float*)d_in[12];
    const float* whh    = (const float*)d_in[13];
    const float* bih    = (const float*)d_in[14];
    const float* bhh    = (const float*)d_in[15];
    const int* src_idx  = (const int*)d_in[16];
    const int* tgt_idx  = (const int*)d_in[17];
    const int* n_steps  = (const int*)d_in[18];

    const int B = in_sizes[0] / (R * L);

    float* wsf = (float*)d_ws;
    float* xw  = wsf;                              // SZ_XW floats
    float* zx  = wsf + SZ_XW;                      // 2*B*R*L floats
    unsigned int* bar = (unsigned int*)(wsf + SZ_XW + 2 * (size_t)B * R * L); // B*64 uints

    const int nbar = B * BARSTRIDE;
    const int prep_items = SZ_XW + nbar;
    nv_prep<<<dim3((prep_items + 255) / 256), dim3(256), 0, stream>>>(
        mean_w, add_w, gsw, gcw, lw, ow, wih, whh, xw, bar, nbar);

    nv_main<<<dim3(NSHARD, B), dim3(BS), 0, stream>>>(
        z0, h0, mean_b, gsb, lb, ob, bih, bhh, src_idx, tgt_idx, n_steps,
        xw, zx, bar, (float*)d_out, B);
}

// Round 5
// 2013.056 us; speedup vs baseline: 3.0597x; 1.6402x over previous
//
#include <hip/hip_runtime.h>

// NeuroVoltron v4: weight-stationary registers. One block per (room, batch-group).
// grid = (R=12, B/G=16) = 192 blocks, 512 threads. Each thread owns one weight
// row in VGPRs (float4 wbuf[16], uniform across roles) for the entire T-loop;
// add_w lives in LDS. Per-step global traffic = z exchange (6 KB) + outputs.
// 12-block device-scope barrier per batch-group per step (padded counter lines).

constexpr int R  = 12;
constexpr int L  = 32;
constexpr int M  = 16;
constexpr int HH = 32;
constexpr int HF = 64;
constexpr int E  = 132;
constexpr int G3 = 96;      // 3*HH
constexpr float DT = 0.1f;

constexpr int G  = 4;       // batch elements per block
constexpr int BS = 512;
constexpr int BARSTRIDE = 64;   // uints per barrier counter (256 B line)

__device__ __forceinline__ float sigmoidf(float x) {
    return 1.0f / (1.0f + __expf(-x));
}
__device__ __forceinline__ float fma4(float4 a, float4 x, float acc) {
    acc = fmaf(a.x, x.x, acc);
    acc = fmaf(a.y, x.y, acc);
    acc = fmaf(a.z, x.z, acc);
    return fmaf(a.w, x.w, acc);
}

__global__ __launch_bounds__(BS) void nv_main(
    const float* __restrict__ z0,     const float* __restrict__ h0,
    const float* __restrict__ mean_w, const float* __restrict__ mean_b,
    const float* __restrict__ add_w,
    const float* __restrict__ gsw,    const float* __restrict__ gsb,
    const float* __restrict__ gcw,
    const float* __restrict__ lw,     const float* __restrict__ lb,
    const float* __restrict__ ow_w,   const float* __restrict__ ob,
    const float* __restrict__ wih,    const float* __restrict__ whh,
    const float* __restrict__ bih,    const float* __restrict__ bhh,
    const int* __restrict__ src_idx,  const int* __restrict__ tgt_idx,
    const int* __restrict__ n_steps_p,
    float* __restrict__ zx, unsigned int* __restrict__ bar,
    float* __restrict__ out, int B)
{
    const int r   = blockIdx.x;       // room
    const int grp = blockIdx.y;       // batch group
    const int tid = threadIdx.x;
    const int T   = n_steps_p[0];
    const int b0  = grp * G;

    // output layout: z_traj (B,T,R,L) | h_f (B,R,HH) | msgs (B,T,E,M)
    float* __restrict__ out_z    = out;
    float* __restrict__ out_hf   = out + (size_t)B * T * R * L;
    float* __restrict__ out_msgs = out_hf + (size_t)B * R * HH;

    __shared__ __align__(16) float wadd_s[11 * L * M];   // [(e*4+c)*32+l] packed f4 over m
    __shared__ __align__(16) float zS[G * R * L];        // [g][room][l]
    __shared__ __align__(16) float hSS[G * HH];          // [g][hh] (own room)
    __shared__ __align__(16) float meanS[G * 11 * M];    // [g][e_local*16+m]
    __shared__ __align__(16) float incS[G * L];
    __shared__ __align__(16) float gateS[G * L];
    __shared__ __align__(16) float shSS[G * HF];
    __shared__ __align__(16) float giSS[G * G3];
    __shared__ __align__(16) float ghSS[G * G3];
    __shared__ int edgeE[11], edgeSrc[11];

    // ---- edge tables for this room ----
    if (tid == 0) {
        int c = 0;
        for (int e = 0; e < E; ++e)
            if (tgt_idx[e] == r) { edgeE[c] = e; edgeSrc[c] = src_idx[e]; ++c; }
    }
    __syncthreads();

    // ---- one-time: load my weight row into registers (uniform wbuf union) ----
    float4 wbuf[16];
#pragma unroll
    for (int k = 0; k < 16; ++k) wbuf[k] = make_float4(0.f, 0.f, 0.f, 0.f);
    float bias = 0.f;
    const float4* wsA = nullptr;
    const float4* wsB = nullptr;
    if (tid < 176) {                       // mean rows: (e_local, m)
        const int el = tid >> 4, m = tid & 15;
        const int row = edgeE[el] * M + m;
        wsA = (const float4*)(mean_w + (size_t)row * L);
        bias = mean_b[row];
    } else if (tid < 272) {                // gh rows (whh)
        const int j = tid - 176, row = r * G3 + j;
        wsA = (const float4*)(whh + (size_t)row * HH);
        bias = bhh[row];
    } else if (tid < 304) {                // gate rows (gsw || gcw)
        const int j = tid - 272, row = r * L + j;
        wsA = (const float4*)(gsw + (size_t)row * L);
        wsB = (const float4*)(gcw + (size_t)row * L);
        bias = gsb[row];
    } else if (tid < 368) {                // silu rows (lw, 64 wide)
        const int j = tid - 304, row = r * HF + j;
        wsA = (const float4*)(lw + (size_t)row * 2 * L);
        wsB = wsA + 8;
        bias = lb[row];
    } else if (tid < 464) {                // gi rows (wih)
        const int j = tid - 368, row = r * G3 + j;
        wsA = (const float4*)(wih + (size_t)row * L);
        bias = bih[row];
    } else if (tid < 496) {                // ow rows (64 wide)
        const int j = tid - 464, row = r * L + j;
        wsA = (const float4*)(ow_w + (size_t)row * HF);
        wsB = wsA + 8;
        bias = ob[row];
    }
    if (wsA) {
#pragma unroll
        for (int k = 0; k < 8; ++k) wbuf[k] = wsA[k];
    }
    if (wsB) {
#pragma unroll
        for (int k = 0; k < 8; ++k) wbuf[8 + k] = wsB[k];
    }

    // ---- one-time: add_w slice -> LDS (transposed, f4-packed over m) ----
    for (int i = tid; i < 11 * L * M; i += BS) {
        const int e = i >> 9, rem = i & 511, l = rem >> 4, m = rem & 15;
        wadd_s[((e * 4 + (m >> 2)) * 32 + l) * 4 + (m & 3)] =
            add_w[((size_t)edgeE[e] * L + l) * M + m];
    }
    // ---- state init ----
    for (int i = tid; i < G * R * L; i += BS) {
        const int g = i / (R * L), rl = i - g * (R * L);
        zS[i] = z0[(size_t)(b0 + g) * R * L + rl];
    }
    for (int i = tid; i < G * HH; i += BS) {
        const int g = i >> 5, hh = i & 31;
        hSS[i] = h0[(size_t)(b0 + g) * R * HH + r * HH + hh];
    }
    __syncthreads();

    unsigned int* __restrict__ mybar = &bar[(size_t)grp * BARSTRIDE];

    for (int t = 0; t < T; ++t) {
        // ---- P1: mean (T0-175) | gh (T176-271) ----
        if (tid < 176) {
            const int el = tid >> 4, m = tid & 15;
            const int eg = edgeE[el], sr = edgeSrc[el];
#pragma unroll
            for (int g = 0; g < G; ++g) {
                const float4* zp = (const float4*)(zS + g * (R * L) + sr * L);
                float a = bias;
#pragma unroll
                for (int c = 0; c < 8; ++c) a = fma4(wbuf[c], zp[c], a);
                meanS[g * 176 + el * 16 + m] = a;
                __builtin_nontemporal_store(
                    a, &out_msgs[((size_t)(b0 + g) * T + t) * (E * M) + eg * 16 + m]);
            }
        } else if (tid < 272) {
            const int j = tid - 176;
#pragma unroll
            for (int g = 0; g < G; ++g) {
                const float4* hp = (const float4*)(hSS + g * HH);
                float a = bias;
#pragma unroll
                for (int c = 0; c < 8; ++c) a = fma4(wbuf[c], hp[c], a);
                ghSS[g * G3 + j] = a;
            }
        }
        __syncthreads();

        // ---- P2: inc (T0-127: (g,l)) from LDS wadd + meanS ----
        if (tid < 128) {
            const int g = tid >> 5, l = tid & 31;
            const float4* mp = (const float4*)(meanS + g * 176);
            const float4* wp = (const float4*)wadd_s;
            float a = 0.f;
#pragma unroll
            for (int e = 0; e < 11; ++e)
#pragma unroll
                for (int c = 0; c < 4; ++c)
                    a = fma4(wp[(e * 4 + c) * 32 + l], mp[e * 4 + c], a);
            incS[g * L + l] = a;
        }
        __syncthreads();

        // ---- P3: gate (272-303) | silu (304-367) | gi (368-463) ----
        if (tid >= 272 && tid < 304) {
            const int j = tid - 272;
#pragma unroll
            for (int g = 0; g < G; ++g) {
                const float4* zp = (const float4*)(zS + g * (R * L) + r * L);
                const float4* ip = (const float4*)(incS + g * L);
                float a = bias;
#pragma unroll
                for (int c = 0; c < 8; ++c) {
                    a = fma4(wbuf[c], zp[c], a);
                    a = fma4(wbuf[8 + c], ip[c], a);
                }
                gateS[g * L + j] = sigmoidf(a);
            }
        } else if (tid >= 304 && tid < 368) {
            const int j = tid - 304;
#pragma unroll
            for (int g = 0; g < G; ++g) {
                const float4* zp = (const float4*)(zS + g * (R * L) + r * L);
                const float4* ip = (const float4*)(incS + g * L);
                float a = bias;
#pragma unroll
                for (int c = 0; c < 8; ++c) {
                    a = fma4(wbuf[c], zp[c], a);
                    a = fma4(wbuf[8 + c], ip[c], a);
                }
                shSS[g * HF + j] = a * sigmoidf(a);
            }
        } else if (tid >= 368 && tid < 464) {
            const int j = tid - 368;
#pragma unroll
            for (int g = 0; g < G; ++g) {
                const float4* ip = (const float4*)(incS + g * L);
                float a = bias;
#pragma unroll
                for (int c = 0; c < 8; ++c) a = fma4(wbuf[c], ip[c], a);
                giSS[g * G3 + j] = a;
            }
        }
        __syncthreads();

        // ---- P4: z-out + publish (464-495) | GRU combine (176-303) ----
        const int p = t & 1;
        float* __restrict__ zxp = zx + (size_t)p * B * (R * L);
        if (tid >= 464 && tid < 496) {
            const int j = tid - 464;
#pragma unroll
            for (int g = 0; g < G; ++g) {
                const float4* sp = (const float4*)(shSS + g * HF);
                float a = bias;
#pragma unroll
                for (int c = 0; c < 16; ++c) a = fma4(wbuf[c], sp[c], a);
                const float target = tanhf(a);
                const float zv = zS[g * (R * L) + r * L + j];
                const float znew = zv + DT * gateS[g * L + j] * (target - zv);
                __hip_atomic_store(&zxp[(size_t)(b0 + g) * (R * L) + r * L + j], znew,
                                   __ATOMIC_RELAXED, __HIP_MEMORY_SCOPE_AGENT);
                __builtin_nontemporal_store(
                    znew, &out_z[((size_t)(b0 + g) * T + t) * (R * L) + r * L + j]);
            }
        } else if (tid >= 176 && tid < 304) {
            const int i = tid - 176;
            const int g = i >> 5, hh = i & 31;
            const float ir  = giSS[g * G3 + hh];
            const float iz  = giSS[g * G3 + HH + hh];
            const float inn = giSS[g * G3 + 2 * HH + hh];
            const float hr  = ghSS[g * G3 + hh];
            const float hz  = ghSS[g * G3 + HH + hh];
            const float hnv = ghSS[g * G3 + 2 * HH + hh];
            const float reset = sigmoidf(ir + hr);
            const float upd   = sigmoidf(iz + hz);
            const float nw    = tanhf(inn + reset * hnv);
            hSS[g * HH + hh] = (1.0f - upd) * nw + upd * hSS[g * HH + hh];
        }
        __syncthreads();

        // ---- 12-block barrier for this batch group ----
        if (tid == 0) {
            __hip_atomic_fetch_add(mybar, 1u, __ATOMIC_RELEASE, __HIP_MEMORY_SCOPE_AGENT);
            const unsigned int tgt = (unsigned int)R * (unsigned int)(t + 1);
            while (__hip_atomic_load(mybar, __ATOMIC_RELAXED, __HIP_MEMORY_SCOPE_AGENT) < tgt)
                __builtin_amdgcn_s_sleep(1);
        }
        __syncthreads();

        // ---- refresh all rooms' z for this group's batches ----
        for (int i = tid; i < G * R * L; i += BS) {
            const int g = i / (R * L), rl = i - g * (R * L);
            zS[i] = __hip_atomic_load(&zxp[(size_t)(b0 + g) * (R * L) + rl],
                                      __ATOMIC_RELAXED, __HIP_MEMORY_SCOPE_AGENT);
        }
        __syncthreads();
    }

    // ---- final h ----
    for (int i = tid; i < G * HH; i += BS) {
        const int g = i >> 5, hh = i & 31;
        __builtin_nontemporal_store(
            hSS[i], &out_hf[(size_t)(b0 + g) * R * HH + r * HH + hh]);
    }
}

extern "C" void kernel_launch(void* const* d_in, const int* in_sizes, int n_in,
                              void* d_out, int out_size, void* d_ws, size_t ws_size,
                              hipStream_t stream) {
    const float* z0     = (const float*)d_in[0];
    const float* h0     = (const float*)d_in[1];
    const float* mean_w = (const float*)d_in[2];
    const float* mean_b = (const float*)d_in[3];
    const float* add_w  = (const float*)d_in[4];
    const float* gsw    = (const float*)d_in[5];
    const float* gsb    = (const float*)d_in[6];
    const float* gcw    = (const float*)d_in[7];
    const float* lw     = (const float*)d_in[8];
    const float* lb     = (const float*)d_in[9];
    const float* ow_w   = (const float*)d_in[10];
    const float* ob     = (const float*)d_in[11];
    const float* wih    = (const float*)d_in[12];
    const float* whh    = (const float*)d_in[13];
    const float* bih    = (const float*)d_in[14];
    const float* bhh    = (const float*)d_in[15];
    const int* src_idx  = (const int*)d_in[16];
    const int* tgt_idx  = (const int*)d_in[17];
    const int* n_steps  = (const int*)d_in[18];

    const int B  = in_sizes[0] / (R * L);
    const int NG = B / G;   // batch groups

    float* wsf = (float*)d_ws;
    float* zx  = wsf;                                        // 2*B*R*L floats
    unsigned int* bar = (unsigned int*)(wsf + 2 * (size_t)B * R * L); // NG*64 uints

    hipMemsetAsync(bar, 0, (size_t)NG * BARSTRIDE * sizeof(unsigned int), stream);

    nv_main<<<dim3(R, NG), dim3(BS), 0, stream>>>(
        z0, h0, mean_w, mean_b, add_w, gsw, gsb, gcw, lw, lb, ow_w, ob,
        wih, whh, bih, bhh, src_idx, tgt_idx, n_steps,
        zx, bar, (float*)d_out, B);
}